// Round 14
// baseline (88.882 us; speedup 1.0000x reference)
//
#include <hip/hip_runtime.h>

typedef _Float16 half8 __attribute__((ext_vector_type(8)));
typedef float f32x4 __attribute__((ext_vector_type(4)));

#define NPTS   4096
#define BATCH  16
#define BLOCK  256       // 4 waves
#define CHUNK  2048      // others staged per LDS pass (32 KB)
#define NCHUNK 2
#define NBLK   1024      // 2 dir x 16 batch x 32 self-tiles(128) = 4 blocks/CU
#define NFRAG  8         // A-fragments per wave (128 selves)

// dist(s,o) = |s|^2 + (s.g + q), g = -2o, q = |o|^2, f16 hi/lo split.
// 16-B record/other: R = [ghx,ghy,ghz,glx,gly,glz,qh,ql]  (verified R9-R13).
// R14: mfma_f32_16x16x32_f16 (4-VGPR accumulators -> pipelinable folds).
// B: every lane reads the SAME record of its column n=lane&15 (quads
// broadcast), so B[k=quad*8+j][n] = R[j]. A per quad (m = lane&15):
//   quad0: [shx,shy,shz,0,0,0,1,0]        -> sh.gh + qh
//   quad1: [slx,sly,slz,shx,shy,shz,0,1]  -> sl.gh + sh.gl + ql
//   quad2/3: 0                             (B content there irrelevant)
// C/D (verified m89/m91): col = lane&15, row = (lane>>4)*4 + reg.
__global__ __launch_bounds__(BLOCK, 4) void chamfer_mfma_kernel(
    const float* __restrict__ p1, const float* __restrict__ p2,
    float* __restrict__ partial)
{
    __shared__ half8 REC[CHUNK];    // 32 KB; combine area reuses it after loop

    const int tid  = threadIdx.x;
    const int lane = tid & 63;
    const int n    = lane & 15;     // tile col (other) / A row m (self)
    const int quad = lane >> 4;     // K-quad
    const int wv   = tid >> 6;      // 0..3 = others quarter
    const int blk  = blockIdx.x;
    const int j    = blk & 31;      // self tile of 128
    const int b    = (blk >> 5) & 15;
    const int dir  = blk >> 9;

    const float* selfp  = (dir == 0 ? p1 : p2) + (size_t)b * NPTS * 3;
    const float* otherp = (dir == 0 ? p2 : p1) + (size_t)b * NPTS * 3;

    // ---- 8 A-fragments: frag f covers selves j*128 + f*16 + m ----
    half8 af[NFRAG];
    {
        const _Float16 c0 = (_Float16)0.f, c1 = (_Float16)1.f;
#pragma unroll
        for (int f = 0; f < NFRAG; ++f) {
            const int i0 = (j * 128 + f * 16 + n) * 3;
            float x = selfp[i0], y = selfp[i0 + 1], z = selfp[i0 + 2];
            _Float16 hx = (_Float16)x, hy = (_Float16)y, hz = (_Float16)z;
            half8 a;
            if (quad == 0) {
                a[0] = hx; a[1] = hy; a[2] = hz;
                a[3] = c0; a[4] = c0; a[5] = c0; a[6] = c1; a[7] = c0;
            } else if (quad == 1) {
                a[0] = (_Float16)(x - (float)hx);
                a[1] = (_Float16)(y - (float)hy);
                a[2] = (_Float16)(z - (float)hz);
                a[3] = hx; a[4] = hy; a[5] = hz; a[6] = c0; a[7] = c1;
            } else {
                a[0]=c0; a[1]=c0; a[2]=c0; a[3]=c0;
                a[4]=c0; a[5]=c0; a[6]=c0; a[7]=c0;
            }
            af[f] = a;
        }
    }

    f32x4 m[NFRAG];
    f32x4 zc = {0.f, 0.f, 0.f, 0.f};
#pragma unroll
    for (int f = 0; f < NFRAG; ++f)
        m[f] = (f32x4){3.4e38f, 3.4e38f, 3.4e38f, 3.4e38f};

    for (int c = 0; c < NCHUNK; ++c) {
        __syncthreads();
        {   // Stage 8 others/thread as records (contiguous b128 writes).
            const float4* src = (const float4*)(otherp + (size_t)c * CHUNK * 3);
            float4 v0 = src[tid * 6 + 0], v1 = src[tid * 6 + 1];
            float4 v2 = src[tid * 6 + 2], v3 = src[tid * 6 + 3];
            float4 v4 = src[tid * 6 + 4], v5 = src[tid * 6 + 5];
            float ox[8] = {v0.x, v0.w, v1.z, v2.y, v3.x, v3.w, v4.z, v5.y};
            float oy[8] = {v0.y, v1.x, v1.w, v2.z, v3.y, v4.x, v4.w, v5.z};
            float oz[8] = {v0.z, v1.y, v2.x, v2.w, v3.z, v4.y, v5.x, v5.w};
#pragma unroll
            for (int k = 0; k < 8; ++k) {
                float gx = -2.f * ox[k], gy = -2.f * oy[k], gz = -2.f * oz[k];
                float q  = fmaf(ox[k], ox[k], fmaf(oy[k], oy[k], oz[k] * oz[k]));
                _Float16 ghx = (_Float16)gx, ghy = (_Float16)gy, ghz = (_Float16)gz;
                half8 r;
                r[0] = ghx; r[1] = ghy; r[2] = ghz;
                r[3] = (_Float16)(gx - (float)ghx);
                r[4] = (_Float16)(gy - (float)ghy);
                r[5] = (_Float16)(gz - (float)ghz);
                _Float16 qh = (_Float16)q;
                r[6] = qh;
                r[7] = (_Float16)(q - (float)qh);
                REC[tid * 8 + k] = r;
            }
        }
        __syncthreads();
        // This wave's 512-other quarter: 32 tiles of 16, 2 tiles/iter.
        const half8* rp = REC + wv * 512 + n;
#pragma unroll 2
        for (int t = 0; t < 16; ++t) {
            half8 b0 = rp[(2 * t + 0) * 16];
            half8 b1 = rp[(2 * t + 1) * 16];
#pragma unroll
            for (int f = 0; f < NFRAG; ++f) {
                f32x4 o0 = __builtin_amdgcn_mfma_f32_16x16x32_f16(af[f], b0, zc, 0, 0, 0);
                f32x4 o1 = __builtin_amdgcn_mfma_f32_16x16x32_f16(af[f], b1, zc, 0, 0, 0);
#pragma unroll
                for (int r = 0; r < 4; ++r)
                    m[f][r] = fminf(fminf(o0[r], o1[r]), m[f][r]);  // v_min3
            }
        }
    }

    // ---- Epilogue: min over cols n (low 4 lane bits), cross-wave combine ----
#pragma unroll
    for (int mask = 1; mask <= 8; mask <<= 1) {
#pragma unroll
        for (int f = 0; f < NFRAG; ++f)
#pragma unroll
            for (int r = 0; r < 4; ++r)
                m[f][r] = fminf(m[f][r], __shfl_xor((float)m[f][r], mask, 64));
    }
    __syncthreads();                 // REC dead; reuse as combine area
    float* CW = (float*)REC;         // [4 waves][136]
    if (n == 0) {                    // one lane per (quad) holds rows quad*4+r
#pragma unroll
        for (int f = 0; f < NFRAG; ++f)
#pragma unroll
            for (int r = 0; r < 4; ++r)
                CW[wv * 136 + f * 16 + quad * 4 + r] = m[f][r];
    }
    __syncthreads();

    float d = 0.f;
    if (tid < 128) {                 // final per-self min + ssq
        float mn = fminf(fminf(CW[tid], CW[136 + tid]),
                         fminf(CW[272 + tid], CW[408 + tid]));
        const int i0 = (j * 128 + tid) * 3;
        float x = selfp[i0], y = selfp[i0 + 1], z = selfp[i0 + 2];
        d = fmaf(x, x, fmaf(y, y, z * z)) + mn;
    }
#pragma unroll
    for (int off = 32; off > 0; off >>= 1) d += __shfl_down(d, off, 64);
    __shared__ float ws4[4];
    if (lane == 0) ws4[wv] = d;
    __syncthreads();
    if (tid == 0)
        partial[blk] = ws4[0] + ws4[1] + ws4[2] + ws4[3];
}

__global__ __launch_bounds__(256) void chamfer_reduce(
    const float* __restrict__ partial, float* __restrict__ out)
{
    float s = 0.f;
    for (int i = threadIdx.x; i < NBLK; i += 256) s += partial[i];
#pragma unroll
    for (int off = 32; off > 0; off >>= 1) s += __shfl_down(s, off, 64);
    __shared__ float ws4[4];
    int lane = threadIdx.x & 63, wv = threadIdx.x >> 6;
    if (lane == 0) ws4[wv] = s;
    __syncthreads();
    if (threadIdx.x == 0)
        out[0] = (ws4[0] + ws4[1] + ws4[2] + ws4[3]) * (1.0f / BATCH);
}

extern "C" void kernel_launch(void* const* d_in, const int* in_sizes, int n_in,
                              void* d_out, int out_size, void* d_ws, size_t ws_size,
                              hipStream_t stream) {
    const float* p1 = (const float*)d_in[0];
    const float* p2 = (const float*)d_in[1];
    float* out = (float*)d_out;
    float* partial = (float*)d_ws;   // 1024 floats; fully overwritten each call

    chamfer_mfma_kernel<<<dim3(NBLK), dim3(BLOCK), 0, stream>>>(p1, p2, partial);
    chamfer_reduce<<<dim3(1), dim3(256), 0, stream>>>(partial, out);
}